// Round 12
// baseline (60.559 us; speedup 1.0000x reference)
//
#include <hip/hip_runtime.h>

#define N_EMB   8192
#define D_EMB   128
#define NSTEPS  201
#define NB      128                  // 8192 / 64 tiles per dim
#define TBLOCKS (NB*(NB+1)/2)        // 8256 upper-tri tiles incl. diagonal
#define NCOPY   16                   // replicated global histogram copies
#define NHIST   8                    // per-half-wave LDS copies (per sign table)
#define PGRID   2048                 // persistent grid (8 blocks/CU)

typedef __attribute__((ext_vector_type(8))) short bf16x8;
typedef __attribute__((ext_vector_type(4))) float f32x4;

// packed per-bin accumulator: (count << 21) | fq, fq = round(frac*1024)
#define CNT_SHIFT  21
#define FRAC_MASK  ((1u << CNT_SHIFT) - 1u)
#define NZERO      (NCOPY * 2 * NSTEPS)      // floats to zero in ghist

__device__ __forceinline__ unsigned short f2bf(float f) {
  unsigned int u = __builtin_bit_cast(unsigned int, f);
  u = (u + 0x7fffu + ((u >> 16) & 1u)) >> 16;   // RNE fp32 -> bf16
  return (unsigned short)u;
}

// ---- pre-pass: fp32 -> bf16 fragment-tiled; zeroes ghist (no memset) ----
__global__ __launch_bounds__(256) void convert_kernel(
    const float* __restrict__ x1, const float* __restrict__ x2,
    unsigned short* __restrict__ x1b, unsigned short* __restrict__ x2b,
    float* __restrict__ ghist)
{
  int t = blockIdx.x * 256 + threadIdx.x;
  if (t < NZERO) ghist[t] = 0.0f;
  const float*    src = (t < 131072) ? x1  : x2;
  unsigned short* dst = (t < 131072) ? x1b : x2b;
  int tt  = t & 131071;
  int r   = tt >> 4;
  int c16 = tt & 15;
  const float4* g = reinterpret_cast<const float4*>(src + ((size_t)r << 7) + c16*8);
  float4 v0 = g[0], v1 = g[1];
  int R = r >> 4, fr = r & 15, K = c16 >> 2, kg = c16 & 3;
  size_t chunk = ((size_t)(R*4 + K) << 6) + (size_t)(kg*16 + fr);
  uint4 p;
  p.x = f2bf(v0.x) | ((unsigned int)f2bf(v0.y) << 16);
  p.y = f2bf(v0.z) | ((unsigned int)f2bf(v0.w) << 16);
  p.z = f2bf(v1.x) | ((unsigned int)f2bf(v1.y) << 16);
  p.w = f2bf(v1.z) | ((unsigned int)f2bf(v1.w) << 16);
  *reinterpret_cast<uint4*>(dst + chunk*8) = p;
}

// ============ main pass: both histograms, persistent, strip-major, 8 blocks/CU ============
__global__ __launch_bounds__(256, 8) void main_kernel(
    const unsigned short* __restrict__ x1b, const unsigned short* __restrict__ x2b,
    const float* __restrict__ t1g, const float* __restrict__ t2g,
    float* __restrict__ ghist)
{
  __shared__ unsigned int whist[2][NHIST][NSTEPS];   // [pos/neg][copy][bin]

  const int tid = threadIdx.x;
  for (int b = tid; b < 2*NHIST*NSTEPS; b += 256) ((unsigned int*)whist)[b] = 0u;

  const int lane = tid & 63;
  const int w    = tid >> 6;
  const int wr   = w >> 1, wc = w & 1;
  const int fr   = lane & 15;
  const int kg   = lane >> 4;
  const int rbase = kg * 4;
  unsigned int* whP = &whist[0][(w << 1) | (kg & 1)][0];   // 8 copies, 32 lanes each
  const int NEGOFF = NHIST * NSTEPS;          // element offset pos-table -> neg-table

  // persistent range: tiles [bid*TBLOCKS/2048, (bid+1)*TBLOCKS/2048)
  const int t0  = (int)(((unsigned)blockIdx.x       * (unsigned)TBLOCKS) >> 11);
  const int t1e = (int)((((unsigned)blockIdx.x + 1u) * (unsigned)TBLOCKS) >> 11);

  __syncthreads();                            // whist zeroing visible

  int prev_bj = -1;
  bf16x8 bQ[2][4];                            // cached B frags [n-tile][ks] (32 VGPR)
  float  T1v[2];

  for (int t = t0; t < t1e; ++t) {
    // strip-major coords: bj = strip, bi = t - bj(bj+1)/2, bi <= bj
    int j = (int)((sqrtf(8.0f*(float)t + 1.0f) - 1.0f) * 0.5f);
    while ((j+1)*(j+2)/2 <= t) ++j;
    while (j*(j+1)/2 > t) --j;
    const int bi = t - j*(j+1)/2;
    const int gi0 = bi*64, gj0 = j*64;
    const bool full = (bi != j);

    if (j != prev_bj) {                       // strip crossing: reload B frags + T1
      prev_bj = j;
      const int Rb = (gj0 >> 4) + wc*2;
#pragma unroll
      for (int ks = 0; ks < 4; ++ks) {
        bQ[0][ks] = *reinterpret_cast<const bf16x8*>(x2b + ((((size_t)Rb    *4 + ks)*64 + lane) << 3));
        bQ[1][ks] = *reinterpret_cast<const bf16x8*>(x2b + ((((size_t)(Rb+1)*4 + ks)*64 + lane) << 3));
      }
      T1v[0] = t1g[gj0 + wc*32 + fr];
      T1v[1] = t1g[gj0 + wc*32 + 16 + fr];
    }

    const int Ra = (gi0 >> 4) + wr*2;
    f32x4 acc00 = {0.f,0.f,0.f,0.f}, acc01 = {0.f,0.f,0.f,0.f};
    f32x4 acc10 = {0.f,0.f,0.f,0.f}, acc11 = {0.f,0.f,0.f,0.f};
#pragma unroll
    for (int ks = 0; ks < 4; ++ks) {
      bf16x8 a0 = *reinterpret_cast<const bf16x8*>(x1b + ((((size_t)Ra    *4 + ks)*64 + lane) << 3));
      bf16x8 a1 = *reinterpret_cast<const bf16x8*>(x1b + ((((size_t)(Ra+1)*4 + ks)*64 + lane) << 3));
      acc00 = __builtin_amdgcn_mfma_f32_16x16x32_bf16(a0, bQ[0][ks], acc00, 0, 0, 0);
      acc01 = __builtin_amdgcn_mfma_f32_16x16x32_bf16(a0, bQ[1][ks], acc01, 0, 0, 0);
      acc10 = __builtin_amdgcn_mfma_f32_16x16x32_bf16(a1, bQ[0][ks], acc10, 0, 0, 0);
      acc11 = __builtin_amdgcn_mfma_f32_16x16x32_bf16(a1, bQ[1][ks], acc11, 0, 0, 0);
    }

    // row targets from global (L1/L2-resident; 16 lanes share each address)
    float T2v[2][4];
#pragma unroll
    for (int tm = 0; tm < 2; ++tm)
#pragma unroll
      for (int rr = 0; rr < 4; ++rr) T2v[tm][rr] = t2g[gi0 + wr*32 + tm*16 + rbase + rr];

    // C/D layout (m89/m91): col = lane&15, row = (lane>>4)*4 + reg
    auto dep = [&](const f32x4& a, int tm, int tn) {
      const int lj = wc*32 + tn*16 + fr;
      const float t1v = T1v[tn];
#pragma unroll
      for (int rr = 0; rr < 4; ++rr) {
        const int li = wr*32 + tm*16 + rbase + rr;
        bool pos = (T2v[tm][rr] * t1v > 0.0f);
        float uu = fmaf(a[rr], 102400.0f, 102400.5f);
        int   iu = (int)uu;
        int  idx = iu >> 10;
        idx = idx < 0 ? 0 : (idx > NSTEPS-1 ? NSTEPS-1 : idx);
        unsigned int pk = (1u << CNT_SHIFT) | (unsigned int)(iu & 1023);
        unsigned int* dst = whP + (pos ? 0 : NEGOFF) + idx;
        if (full || (lj > li)) atomicAdd(dst, pk);
      }
    };
    dep(acc00, 0, 0); dep(acc01, 0, 1);
    dep(acc10, 1, 0); dep(acc11, 1, 1);
  }
  __syncthreads();

  // unpack + flush once per sign table:
  // h[b] = cnt[b] - fr[b]/1024 + fr[b-1]/1024 ; h[200] = cnt[200] + fr[199]/1024
  float* gh = ghist + (size_t)(blockIdx.x & (NCOPY-1)) * (2*NSTEPS);
  if (tid < NSTEPS) {
    const int b = tid;
    const float inv = 1.0f / 1024.0f;
#pragma unroll
    for (int sg = 0; sg < 2; ++sg) {
      unsigned int cp = 0; float fp = 0.f, fpm1 = 0.f;
#pragma unroll
      for (int ww = 0; ww < NHIST; ++ww) {
        unsigned int vp = whist[sg][ww][b];
        cp += vp >> CNT_SHIFT;  fp += (float)(vp & FRAC_MASK);
        if (b > 0) fpm1 += (float)(whist[sg][ww][b-1] & FRAC_MASK);
      }
      float hv = (b == NSTEPS-1) ? ((float)cp + fpm1 * inv)
                                 : ((float)cp - fp * inv + fpm1 * inv);
      if (hv != 0.0f) atomicAdd(&gh[sg*NSTEPS + b], hv);
    }
  }
}

// ============ finalize: sum copies, cumsum pos, dot with neg ============
__global__ void finalize_kernel(const float* __restrict__ ghist,
                                float* __restrict__ out)
{
  __shared__ float hp[NSTEPS], hn[NSTEPS];
  const int tid = threadIdx.x;
  if (tid < NSTEPS) {
    float sp = 0.f, sn = 0.f;
#pragma unroll
    for (int c = 0; c < NCOPY; ++c) {
      sp += ghist[(size_t)c*(2*NSTEPS) + tid];
      sn += ghist[(size_t)c*(2*NSTEPS) + NSTEPS + tid];
    }
    hp[tid] = sp; hn[tid] = sn;
  }
  __syncthreads();
  if (tid == 0) {
    const float TOT = 33550336.0f;            // N*(N-1)/2
    float np = 0.f;
    for (int b = 0; b < NSTEPS; ++b) np += hp[b];
    float nn = TOT - np;
    float ip  = 1.0f / fmaxf(np, 1.0f);
    float in_ = 1.0f / fmaxf(nn, 1.0f);
    float cdf = 0.f, loss = 0.f;
    for (int b = 0; b < NSTEPS; ++b) {
      cdf  += hp[b] * ip;
      loss += hn[b] * in_ * cdf;
    }
    out[0] = loss;
  }
}

extern "C" void kernel_launch(void* const* d_in, const int* in_sizes, int n_in,
                              void* d_out, int out_size, void* d_ws, size_t ws_size,
                              hipStream_t stream) {
  const float* x1 = (const float*)d_in[0];
  const float* x2 = (const float*)d_in[1];
  const float* t1 = (const float*)d_in[2];
  const float* t2 = (const float*)d_in[3];
  float* out = (float*)d_out;

  const size_t BF_BYTES = (size_t)N_EMB * D_EMB * sizeof(unsigned short);  // 2 MB each
  char* p = (char*)d_ws;
  unsigned short* x1b   = (unsigned short*)p;   p += BF_BYTES;
  unsigned short* x2b   = (unsigned short*)p;   p += BF_BYTES;
  float*          ghist = (float*)p;

  convert_kernel<<<(2*N_EMB*D_EMB/8 + 255)/256, 256, 0, stream>>>(x1, x2, x1b, x2b, ghist);
  main_kernel<<<PGRID, 256, 0, stream>>>(x1b, x2b, t1, t2, ghist);
  finalize_kernel<<<1, 256, 0, stream>>>(ghist, out);
}

// Round 13
// 41.433 us; speedup vs baseline: 1.4616x; 1.4616x over previous
//
#include <hip/hip_runtime.h>

#define N_EMB   8192
#define D_EMB   128
#define NSTEPS  201
#define NB      128                  // 8192 / 64 tiles per dim
#define TBLOCKS (NB*(NB+1)/2)        // 8256 upper-tri tiles incl. diagonal
#define NCOPY   16                   // replicated global histogram copies
#define NHIST   16                   // per-quarter-wave LDS copies (per sign table)
#define PGRID   1536                 // persistent grid (6 blocks/CU, LDS-limited)

typedef __attribute__((ext_vector_type(8))) short bf16x8;
typedef __attribute__((ext_vector_type(4))) float f32x4;

// packed per-bin accumulator: (count << 21) | fq, fq = round(frac*1024)
#define CNT_SHIFT  21
#define FRAC_MASK  ((1u << CNT_SHIFT) - 1u)
#define NZERO      (NCOPY * 2 * NSTEPS)      // floats to zero in ghist

__device__ __forceinline__ unsigned short f2bf(float f) {
  unsigned int u = __builtin_bit_cast(unsigned int, f);
  u = (u + 0x7fffu + ((u >> 16) & 1u)) >> 16;   // RNE fp32 -> bf16
  return (unsigned short)u;
}

// ---- pre-pass: fp32 -> bf16 fragment-tiled; zeroes ghist (no memset) ----
__global__ __launch_bounds__(256) void convert_kernel(
    const float* __restrict__ x1, const float* __restrict__ x2,
    unsigned short* __restrict__ x1b, unsigned short* __restrict__ x2b,
    float* __restrict__ ghist)
{
  int t = blockIdx.x * 256 + threadIdx.x;
  if (t < NZERO) ghist[t] = 0.0f;
  const float*    src = (t < 131072) ? x1  : x2;
  unsigned short* dst = (t < 131072) ? x1b : x2b;
  int tt  = t & 131071;
  int r   = tt >> 4;
  int c16 = tt & 15;
  const float4* g = reinterpret_cast<const float4*>(src + ((size_t)r << 7) + c16*8);
  float4 v0 = g[0], v1 = g[1];
  int R = r >> 4, fr = r & 15, K = c16 >> 2, kg = c16 & 3;
  size_t chunk = ((size_t)(R*4 + K) << 6) + (size_t)(kg*16 + fr);
  uint4 p;
  p.x = f2bf(v0.x) | ((unsigned int)f2bf(v0.y) << 16);
  p.y = f2bf(v0.z) | ((unsigned int)f2bf(v0.w) << 16);
  p.z = f2bf(v1.x) | ((unsigned int)f2bf(v1.y) << 16);
  p.w = f2bf(v1.z) | ((unsigned int)f2bf(v1.w) << 16);
  *reinterpret_cast<uint4*>(dst + chunk*8) = p;
}

// ============ main pass: both histograms, persistent, nested strip loops ============
__global__ __launch_bounds__(256, 6) void main_kernel(
    const unsigned short* __restrict__ x1b, const unsigned short* __restrict__ x2b,
    const float* __restrict__ t1g, const float* __restrict__ t2g,
    float* __restrict__ ghist)
{
  __shared__ unsigned int whist[2][NHIST][NSTEPS];   // [pos/neg][copy][bin]

  const int tid = threadIdx.x;
  for (int b = tid; b < 2*NHIST*NSTEPS; b += 256) ((unsigned int*)whist)[b] = 0u;

  const int lane = tid & 63;
  const int w    = tid >> 6;
  const int wr   = w >> 1, wc = w & 1;
  const int fr   = lane & 15;
  const int kg   = lane >> 4;
  const int rbase = kg * 4;
  unsigned int* whP = &whist[0][(w << 2) | kg][0];
  const int NEGOFF = NHIST * NSTEPS;          // element offset pos-table -> neg-table

  // XCD-aware swizzle (bijective: 1536 = 8 XCDs * 192): same-XCD blocks get
  // contiguous tile ranges -> A/B panels shared within one L2
  const unsigned bid = ((unsigned)blockIdx.x & 7u) * 192u + ((unsigned)blockIdx.x >> 3);

  // persistent range: tiles [bid*43/8, (bid+1)*43/8)  (8256/1536 = 43/8)
  const int t0  = (int)((bid      * 43u) >> 3);
  const int t1e = (int)(((bid+1u) * 43u) >> 3);

  __syncthreads();                            // whist zeroing visible

  // decode starting strip once
  int j = (int)((sqrtf(8.0f*(float)t0 + 1.0f) - 1.0f) * 0.5f);
  while ((j+1)*(j+2)/2 <= t0) ++j;
  while (j*(j+1)/2 > t0) --j;
  int bi = t0 - j*(j+1)/2;

  int t = t0;
  while (t < t1e) {
    // ---- strip j: load B frags + T1 (outer loop) ----
    const int gj0 = j*64;
    const int Rb = (gj0 >> 4) + wc*2;
    bf16x8 bQ[2][4];
#pragma unroll
    for (int ks = 0; ks < 4; ++ks) {
      bQ[0][ks] = *reinterpret_cast<const bf16x8*>(x2b + ((((size_t)Rb    *4 + ks)*64 + lane) << 3));
      bQ[1][ks] = *reinterpret_cast<const bf16x8*>(x2b + ((((size_t)(Rb+1)*4 + ks)*64 + lane) << 3));
    }
    float T1v0 = t1g[gj0 + wc*32 + fr];
    float T1v1 = t1g[gj0 + wc*32 + 16 + fr];

    const int cnt = min(j + 1 - bi, t1e - t);
    const int bi_end = bi + cnt;

    // ---- inner loop over rows of the strip: affine addresses, pipelineable ----
    for (; bi < bi_end; ++bi) {
      const int gi0 = bi*64;
      const bool full = (bi != j);
      const int Ra = (gi0 >> 4) + wr*2;

      // row targets early (independent of MFMA)
      float T2v[2][4];
#pragma unroll
      for (int tm = 0; tm < 2; ++tm)
#pragma unroll
        for (int rr = 0; rr < 4; ++rr) T2v[tm][rr] = t2g[gi0 + wr*32 + tm*16 + rbase + rr];

      f32x4 acc00 = {0.f,0.f,0.f,0.f}, acc01 = {0.f,0.f,0.f,0.f};
      f32x4 acc10 = {0.f,0.f,0.f,0.f}, acc11 = {0.f,0.f,0.f,0.f};
#pragma unroll
      for (int ks = 0; ks < 4; ++ks) {
        bf16x8 a0 = *reinterpret_cast<const bf16x8*>(x1b + ((((size_t)Ra    *4 + ks)*64 + lane) << 3));
        bf16x8 a1 = *reinterpret_cast<const bf16x8*>(x1b + ((((size_t)(Ra+1)*4 + ks)*64 + lane) << 3));
        acc00 = __builtin_amdgcn_mfma_f32_16x16x32_bf16(a0, bQ[0][ks], acc00, 0, 0, 0);
        acc01 = __builtin_amdgcn_mfma_f32_16x16x32_bf16(a0, bQ[1][ks], acc01, 0, 0, 0);
        acc10 = __builtin_amdgcn_mfma_f32_16x16x32_bf16(a1, bQ[0][ks], acc10, 0, 0, 0);
        acc11 = __builtin_amdgcn_mfma_f32_16x16x32_bf16(a1, bQ[1][ks], acc11, 0, 0, 0);
      }

      // C/D layout (m89/m91): col = lane&15, row = (lane>>4)*4 + reg
      auto dep = [&](const f32x4& a, int tm, float t1v, int tn) {
        const int lj = wc*32 + tn*16 + fr;
#pragma unroll
        for (int rr = 0; rr < 4; ++rr) {
          const int li = wr*32 + tm*16 + rbase + rr;
          bool pos = (T2v[tm][rr] * t1v > 0.0f);
          float uu = fmaf(a[rr], 102400.0f, 102400.5f);
          int   iu = (int)uu;
          int  idx = iu >> 10;
          idx = idx < 0 ? 0 : (idx > NSTEPS-1 ? NSTEPS-1 : idx);
          unsigned int pk = (1u << CNT_SHIFT) | (unsigned int)(iu & 1023);
          unsigned int* dst = whP + (pos ? 0 : NEGOFF) + idx;
          if (full || (lj > li)) atomicAdd(dst, pk);
        }
      };
      dep(acc00, 0, T1v0, 0); dep(acc01, 0, T1v1, 1);
      dep(acc10, 1, T1v0, 0); dep(acc11, 1, T1v1, 1);
      ++t;
    }
    bi = 0; ++j;                              // next strip
  }
  __syncthreads();

  // unpack + flush once per sign table:
  // h[b] = cnt[b] - fr[b]/1024 + fr[b-1]/1024 ; h[200] = cnt[200] + fr[199]/1024
  float* gh = ghist + (size_t)(blockIdx.x & (NCOPY-1)) * (2*NSTEPS);
  if (tid < NSTEPS) {
    const int b = tid;
    const float inv = 1.0f / 1024.0f;
#pragma unroll
    for (int sg = 0; sg < 2; ++sg) {
      unsigned int cp = 0; float fp = 0.f, fpm1 = 0.f;
#pragma unroll
      for (int ww = 0; ww < NHIST; ++ww) {
        unsigned int vp = whist[sg][ww][b];
        cp += vp >> CNT_SHIFT;  fp += (float)(vp & FRAC_MASK);
        if (b > 0) fpm1 += (float)(whist[sg][ww][b-1] & FRAC_MASK);
      }
      float hv = (b == NSTEPS-1) ? ((float)cp + fpm1 * inv)
                                 : ((float)cp - fp * inv + fpm1 * inv);
      if (hv != 0.0f) atomicAdd(&gh[sg*NSTEPS + b], hv);
    }
  }
}

// ============ finalize: sum copies, cumsum pos, dot with neg ============
__global__ void finalize_kernel(const float* __restrict__ ghist,
                                float* __restrict__ out)
{
  __shared__ float hp[NSTEPS], hn[NSTEPS];
  const int tid = threadIdx.x;
  if (tid < NSTEPS) {
    float sp = 0.f, sn = 0.f;
#pragma unroll
    for (int c = 0; c < NCOPY; ++c) {
      sp += ghist[(size_t)c*(2*NSTEPS) + tid];
      sn += ghist[(size_t)c*(2*NSTEPS) + NSTEPS + tid];
    }
    hp[tid] = sp; hn[tid] = sn;
  }
  __syncthreads();
  if (tid == 0) {
    const float TOT = 33550336.0f;            // N*(N-1)/2
    float np = 0.f;
    for (int b = 0; b < NSTEPS; ++b) np += hp[b];
    float nn = TOT - np;
    float ip  = 1.0f / fmaxf(np, 1.0f);
    float in_ = 1.0f / fmaxf(nn, 1.0f);
    float cdf = 0.f, loss = 0.f;
    for (int b = 0; b < NSTEPS; ++b) {
      cdf  += hp[b] * ip;
      loss += hn[b] * in_ * cdf;
    }
    out[0] = loss;
  }
}

extern "C" void kernel_launch(void* const* d_in, const int* in_sizes, int n_in,
                              void* d_out, int out_size, void* d_ws, size_t ws_size,
                              hipStream_t stream) {
  const float* x1 = (const float*)d_in[0];
  const float* x2 = (const float*)d_in[1];
  const float* t1 = (const float*)d_in[2];
  const float* t2 = (const float*)d_in[3];
  float* out = (float*)d_out;

  const size_t BF_BYTES = (size_t)N_EMB * D_EMB * sizeof(unsigned short);  // 2 MB each
  char* p = (char*)d_ws;
  unsigned short* x1b   = (unsigned short*)p;   p += BF_BYTES;
  unsigned short* x2b   = (unsigned short*)p;   p += BF_BYTES;
  float*          ghist = (float*)p;

  convert_kernel<<<(2*N_EMB*D_EMB/8 + 255)/256, 256, 0, stream>>>(x1, x2, x1b, x2b, ghist);
  main_kernel<<<PGRID, 256, 0, stream>>>(x1b, x2b, t1, t2, ghist);
  finalize_kernel<<<1, 256, 0, stream>>>(ghist, out);
}

// Round 14
// 39.638 us; speedup vs baseline: 1.5278x; 1.0453x over previous
//
#include <hip/hip_runtime.h>

#define N_EMB   8192
#define D_EMB   128
#define NSTEPS  201
#define NB      128                  // 8192 / 64 tiles per dim
#define TBLOCKS (NB*(NB+1)/2)        // 8256 upper-tri tiles incl. diagonal
#define NCOPY   16                   // replicated global histogram copies
#define NHIST   16                   // per-quarter-wave LDS copies (per sign table)
#define PGRID   1536                 // persistent grid (6 blocks/CU, LDS-limited)

typedef __attribute__((ext_vector_type(4))) int   i32x4;

// packed per-bin accumulator: (count << 21) | fq, fq = round(frac*1024)
#define CNT_SHIFT  21
#define FRAC_MASK  ((1u << CNT_SHIFT) - 1u)
#define NZERO      (NCOPY * 2 * NSTEPS)      // floats to zero in ghist

// ---- pre-pass: fp32 -> int8 fragment-tiled (per-row scale); zeroes ghist ----
// i8 16x16x64 fragment: lane l holds row (l&15), k = (l>>4)*16 + [0..15] (16 B).
// chunk index ((R*2 + K64)*64 + lane), lane = kg*16 + fr.
__global__ __launch_bounds__(256) void convert_kernel(
    const float* __restrict__ x1, const float* __restrict__ x2,
    signed char* __restrict__ x1q, signed char* __restrict__ x2q,
    float* __restrict__ sc1, float* __restrict__ sc2,
    float* __restrict__ ghist)
{
  int t = blockIdx.x * 256 + threadIdx.x;        // 0 .. 262143
  if (t < NZERO) ghist[t] = 0.0f;
  const bool first = (t < 131072);
  const float* src = first ? x1  : x2;
  signed char* dst = first ? x1q : x2q;
  float*       scd = first ? sc1 : sc2;
  int tt  = t & 131071;
  int r   = tt >> 4;                             // row 0..8191
  int c16 = tt & 15;                             // 8-elem chunk within row
  const float4* g = reinterpret_cast<const float4*>(src + ((size_t)r << 7) + c16*8);
  float4 v0 = g[0], v1 = g[1];

  // row max-abs via 16-lane butterfly (threads of one row are lane-contiguous)
  float m = fmaxf(fmaxf(fmaxf(fabsf(v0.x), fabsf(v0.y)), fmaxf(fabsf(v0.z), fabsf(v0.w))),
                  fmaxf(fmaxf(fabsf(v1.x), fabsf(v1.y)), fmaxf(fabsf(v1.z), fabsf(v1.w))));
#pragma unroll
  for (int d = 1; d < 16; d <<= 1) m = fmaxf(m, __shfl_xor(m, d, 16));

  float qs = 127.0f / m;
  int q0 = (int)rintf(v0.x * qs), q1 = (int)rintf(v0.y * qs);
  int q2 = (int)rintf(v0.z * qs), q3 = (int)rintf(v0.w * qs);
  int q4 = (int)rintf(v1.x * qs), q5 = (int)rintf(v1.y * qs);
  int q6 = (int)rintf(v1.z * qs), q7 = (int)rintf(v1.w * qs);
  uint2 pk;
  pk.x = (q0 & 255) | ((q1 & 255) << 8) | ((q2 & 255) << 16) | ((unsigned)(q3 & 255) << 24);
  pk.y = (q4 & 255) | ((q5 & 255) << 8) | ((q6 & 255) << 16) | ((unsigned)(q7 & 255) << 24);

  // dst byte offset: k = c16*8..+7 -> K64 = c16>>3, kg = (c16>>1)&3, half = c16&1
  int R = r >> 4, fr = r & 15;
  size_t chunk = ((size_t)(R*2 + (c16 >> 3)) << 6) + (size_t)(((c16 >> 1) & 3)*16 + fr);
  *reinterpret_cast<uint2*>(dst + chunk*16 + (c16 & 1)*8) = pk;

  if (c16 == 0) scd[r] = m * (1.0f / 127.0f);
}

// ============ main pass: both histograms, persistent, nested strip loops, i8 MFMA ============
__global__ __launch_bounds__(256, 6) void main_kernel(
    const signed char* __restrict__ x1q, const signed char* __restrict__ x2q,
    const float* __restrict__ sc1g, const float* __restrict__ sc2g,
    const float* __restrict__ t1g, const float* __restrict__ t2g,
    float* __restrict__ ghist)
{
  __shared__ unsigned int whist[2][NHIST][NSTEPS];   // [pos/neg][copy][bin]

  const int tid = threadIdx.x;
  for (int b = tid; b < 2*NHIST*NSTEPS; b += 256) ((unsigned int*)whist)[b] = 0u;

  const int lane = tid & 63;
  const int w    = tid >> 6;
  const int wr   = w >> 1, wc = w & 1;
  const int fr   = lane & 15;
  const int kg   = lane >> 4;
  const int rbase = kg * 4;
  unsigned int* whP = &whist[0][(w << 2) | kg][0];
  const int NEGOFF = NHIST * NSTEPS;          // element offset pos-table -> neg-table

  const i32x4* A = reinterpret_cast<const i32x4*>(x1q);
  const i32x4* B = reinterpret_cast<const i32x4*>(x2q);

  // XCD-aware swizzle (bijective: 1536 = 8 XCDs * 192)
  const unsigned bid = ((unsigned)blockIdx.x & 7u) * 192u + ((unsigned)blockIdx.x >> 3);
  const int t0  = (int)((bid      * 43u) >> 3);
  const int t1e = (int)(((bid+1u) * 43u) >> 3);

  __syncthreads();                            // whist zeroing visible

  // decode starting strip once
  int j = (int)((sqrtf(8.0f*(float)t0 + 1.0f) - 1.0f) * 0.5f);
  while ((j+1)*(j+2)/2 <= t0) ++j;
  while (j*(j+1)/2 > t0) --j;
  int bi = t0 - j*(j+1)/2;

  int t = t0;
  while (t < t1e) {
    // ---- strip j: load B frags + col targets/scales (outer loop) ----
    const int gj0 = j*64;
    const int Rb = (gj0 >> 4) + wc*2;
    i32x4 bQ[2][2];
#pragma unroll
    for (int ks = 0; ks < 2; ++ks) {
      bQ[0][ks] = B[((size_t)(Rb    *2 + ks) << 6) + lane];
      bQ[1][ks] = B[((size_t)((Rb+1)*2 + ks) << 6) + lane];
    }
    float T1v0 = t1g[gj0 + wc*32 + fr];
    float T1v1 = t1g[gj0 + wc*32 + 16 + fr];
    float sB0  = sc2g[gj0 + wc*32 + fr];
    float sB1  = sc2g[gj0 + wc*32 + 16 + fr];

    const int cnt = min(j + 1 - bi, t1e - t);
    const int bi_end = bi + cnt;

    // ---- inner loop over rows of the strip ----
    for (; bi < bi_end; ++bi) {
      const int gi0 = bi*64;
      const bool full = (bi != j);
      const int Ra = (gi0 >> 4) + wr*2;

      // row targets + scales early (independent of MFMA)
      float T2v[2][4], scA[2][4];
#pragma unroll
      for (int tm = 0; tm < 2; ++tm)
#pragma unroll
        for (int rr = 0; rr < 4; ++rr) {
          int gi = gi0 + wr*32 + tm*16 + rbase + rr;
          T2v[tm][rr] = t2g[gi];
          scA[tm][rr] = sc1g[gi] * 102400.0f;
        }

      i32x4 acc00 = {0,0,0,0}, acc01 = {0,0,0,0};
      i32x4 acc10 = {0,0,0,0}, acc11 = {0,0,0,0};
#pragma unroll
      for (int ks = 0; ks < 2; ++ks) {
        i32x4 a0 = A[((size_t)(Ra    *2 + ks) << 6) + lane];
        i32x4 a1 = A[((size_t)((Ra+1)*2 + ks) << 6) + lane];
        acc00 = __builtin_amdgcn_mfma_i32_16x16x64_i8(a0, bQ[0][ks], acc00, 0, 0, 0);
        acc01 = __builtin_amdgcn_mfma_i32_16x16x64_i8(a0, bQ[1][ks], acc01, 0, 0, 0);
        acc10 = __builtin_amdgcn_mfma_i32_16x16x64_i8(a1, bQ[0][ks], acc10, 0, 0, 0);
        acc11 = __builtin_amdgcn_mfma_i32_16x16x64_i8(a1, bQ[1][ks], acc11, 0, 0, 0);
      }

      // C/D layout (m89/m91, shape-determined): col = lane&15, row = (lane>>4)*4 + reg
      auto dep = [&](const i32x4& a, int tm, float t1v, float sBv, int tn) {
        const int lj = wc*32 + tn*16 + fr;
#pragma unroll
        for (int rr = 0; rr < 4; ++rr) {
          const int li = wr*32 + tm*16 + rbase + rr;
          bool pos = (T2v[tm][rr] * t1v > 0.0f);
          // s = ia * sA*sB ; uu = s*102400 + 102400.5 (scale folded)
          float uu = fmaf((float)a[rr], scA[tm][rr] * sBv, 102400.5f);
          int   iu = (int)uu;
          int  idx = iu >> 10;
          idx = idx < 0 ? 0 : (idx > NSTEPS-1 ? NSTEPS-1 : idx);
          unsigned int pkv = (1u << CNT_SHIFT) | (unsigned int)(iu & 1023);
          unsigned int* dst = whP + (pos ? 0 : NEGOFF) + idx;
          if (full || (lj > li)) atomicAdd(dst, pkv);
        }
      };
      dep(acc00, 0, T1v0, sB0, 0); dep(acc01, 0, T1v1, sB1, 1);
      dep(acc10, 1, T1v0, sB0, 0); dep(acc11, 1, T1v1, sB1, 1);
      ++t;
    }
    bi = 0; ++j;                              // next strip
  }
  __syncthreads();

  // unpack + flush once per sign table:
  // h[b] = cnt[b] - fr[b]/1024 + fr[b-1]/1024 ; h[200] = cnt[200] + fr[199]/1024
  float* gh = ghist + (size_t)(blockIdx.x & (NCOPY-1)) * (2*NSTEPS);
  if (tid < NSTEPS) {
    const int b = tid;
    const float inv = 1.0f / 1024.0f;
#pragma unroll
    for (int sg = 0; sg < 2; ++sg) {
      unsigned int cp = 0; float fp = 0.f, fpm1 = 0.f;
#pragma unroll
      for (int ww = 0; ww < NHIST; ++ww) {
        unsigned int vp = whist[sg][ww][b];
        cp += vp >> CNT_SHIFT;  fp += (float)(vp & FRAC_MASK);
        if (b > 0) fpm1 += (float)(whist[sg][ww][b-1] & FRAC_MASK);
      }
      float hv = (b == NSTEPS-1) ? ((float)cp + fpm1 * inv)
                                 : ((float)cp - fp * inv + fpm1 * inv);
      if (hv != 0.0f) atomicAdd(&gh[sg*NSTEPS + b], hv);
    }
  }
}

// ============ finalize: sum copies, cumsum pos, dot with neg ============
__global__ void finalize_kernel(const float* __restrict__ ghist,
                                float* __restrict__ out)
{
  __shared__ float hp[NSTEPS], hn[NSTEPS];
  const int tid = threadIdx.x;
  if (tid < NSTEPS) {
    float sp = 0.f, sn = 0.f;
#pragma unroll
    for (int c = 0; c < NCOPY; ++c) {
      sp += ghist[(size_t)c*(2*NSTEPS) + tid];
      sn += ghist[(size_t)c*(2*NSTEPS) + NSTEPS + tid];
    }
    hp[tid] = sp; hn[tid] = sn;
  }
  __syncthreads();
  if (tid == 0) {
    const float TOT = 33550336.0f;            // N*(N-1)/2
    float np = 0.f;
    for (int b = 0; b < NSTEPS; ++b) np += hp[b];
    float nn = TOT - np;
    float ip  = 1.0f / fmaxf(np, 1.0f);
    float in_ = 1.0f / fmaxf(nn, 1.0f);
    float cdf = 0.f, loss = 0.f;
    for (int b = 0; b < NSTEPS; ++b) {
      cdf  += hp[b] * ip;
      loss += hn[b] * in_ * cdf;
    }
    out[0] = loss;
  }
}

extern "C" void kernel_launch(void* const* d_in, const int* in_sizes, int n_in,
                              void* d_out, int out_size, void* d_ws, size_t ws_size,
                              hipStream_t stream) {
  const float* x1 = (const float*)d_in[0];
  const float* x2 = (const float*)d_in[1];
  const float* t1 = (const float*)d_in[2];
  const float* t2 = (const float*)d_in[3];
  float* out = (float*)d_out;

  const size_t Q_BYTES = (size_t)N_EMB * D_EMB;          // 1 MB each (i8)
  const size_t S_BYTES = (size_t)N_EMB * sizeof(float);  // 32 KB each
  char* p = (char*)d_ws;
  signed char* x1q   = (signed char*)p;   p += Q_BYTES;
  signed char* x2q   = (signed char*)p;   p += Q_BYTES;
  float*       sc1   = (float*)p;         p += S_BYTES;
  float*       sc2   = (float*)p;         p += S_BYTES;
  float*       ghist = (float*)p;

  convert_kernel<<<(2*N_EMB*D_EMB/8 + 255)/256, 256, 0, stream>>>(x1, x2, x1q, x2q, sc1, sc2, ghist);
  main_kernel<<<PGRID, 256, 0, stream>>>(x1q, x2q, sc1, sc2, t1, t2, ghist);
  finalize_kernel<<<1, 256, 0, stream>>>(ghist, out);
}